// Round 1
// baseline (698.901 us; speedup 1.0000x reference)
//
#include <hip/hip_runtime.h>
#include <cstddef>

// Shapes: B=128, T=256, H=128, 4H=512, D=2E=128, GENOME=1e6, OUT*T=256, K_out=32768
// d_out: out[128][256] (32768 f32) then emb[128][256][128] (4194304 f32)
// ws (floats): xg @0 (16777216) | hs @16777216 (4194304) | WhhT @20971520 (65536)
//              | partials @21037056 (1048576)  => ~84.3 MB total

__device__ __forceinline__ float sigm(float x) { return 1.0f / (1.0f + __expf(-x)); }

// ---------- embedding gather: emb[b,t,pair,:] = table[idx[b,t,pair]] ----------
__global__ void k_embed(const int* __restrict__ idx, const float4* __restrict__ table4,
                        float4* __restrict__ emb4) {
  int i = blockIdx.x * blockDim.x + threadIdx.x;   // B*T*2*16 = 1,048,576
  int p = i >> 4, j = i & 15;
  int id = idx[p];
  emb4[(size_t)p * 16 + j] = table4[(size_t)id * 16 + j];
}

// ---------- W_hh (512x128) -> WhhT (128x512) for coalesced register load ----------
__global__ void k_transpose(const float* __restrict__ W, float* __restrict__ Wt) {
  int i = blockIdx.x * 256 + threadIdx.x;          // 65536
  int g = i >> 7, k = i & 127;
  Wt[k * 512 + g] = W[i];
}

// ---------- generic C[M,N] = A[M,K] @ B[N,K]^T, 64x64 tile, k-chunk 64 ----------
// blockIdx.z handles a k-split slab of (kchunks*64); writes to C + z*partstride.
__global__ __launch_bounds__(256) void k_gemm_tn(
    const float* __restrict__ A, const float* __restrict__ Bm, float* __restrict__ C,
    int K, int kchunks, int N, size_t partstride)
{
  __shared__ float As[64][65];   // [m][k], padded
  __shared__ float Bs[64][68];   // [k][n], transposed in LDS, padded
  const int tid = threadIdx.x;
  const int tx = tid & 15, ty = tid >> 4;
  const int m0 = blockIdx.x * 64, n0 = blockIdx.y * 64;
  float acc[4][4] = {};
  size_t kbase = (size_t)blockIdx.z * kchunks * 64;
  for (int kc = 0; kc < kchunks; ++kc) {
    size_t k0 = kbase + (size_t)kc * 64;
    #pragma unroll
    for (int it = 0; it < 4; ++it) {
      int fi = it * 256 + tid;
      int row = fi >> 4, col4 = fi & 15;
      float4 va = *(const float4*)(A + (size_t)(m0 + row) * K + k0 + col4 * 4);
      As[row][col4*4+0] = va.x; As[row][col4*4+1] = va.y;
      As[row][col4*4+2] = va.z; As[row][col4*4+3] = va.w;
      float4 vb = *(const float4*)(Bm + (size_t)(n0 + row) * K + k0 + col4 * 4);
      Bs[col4*4+0][row] = vb.x; Bs[col4*4+1][row] = vb.y;
      Bs[col4*4+2][row] = vb.z; Bs[col4*4+3][row] = vb.w;
    }
    __syncthreads();
    #pragma unroll 8
    for (int k = 0; k < 64; ++k) {
      float a0 = As[ty*4+0][k], a1 = As[ty*4+1][k], a2 = As[ty*4+2][k], a3 = As[ty*4+3][k];
      float b0 = Bs[k][tx*4+0], b1 = Bs[k][tx*4+1], b2 = Bs[k][tx*4+2], b3 = Bs[k][tx*4+3];
      acc[0][0] += a0*b0; acc[0][1] += a0*b1; acc[0][2] += a0*b2; acc[0][3] += a0*b3;
      acc[1][0] += a1*b0; acc[1][1] += a1*b1; acc[1][2] += a1*b2; acc[1][3] += a1*b3;
      acc[2][0] += a2*b0; acc[2][1] += a2*b1; acc[2][2] += a2*b2; acc[2][3] += a2*b3;
      acc[3][0] += a3*b0; acc[3][1] += a3*b1; acc[3][2] += a3*b2; acc[3][3] += a3*b3;
    }
    __syncthreads();
  }
  float* Cp = C + (size_t)blockIdx.z * partstride;
  #pragma unroll
  for (int i = 0; i < 4; ++i) {
    float4 v = make_float4(acc[i][0], acc[i][1], acc[i][2], acc[i][3]);
    *(float4*)(Cp + (size_t)(m0 + ty*4 + i) * N + n0 + tx*4) = v;
  }
}

// ---------- persistent LSTM scan: one block per batch row, 512 threads ----------
__global__ __launch_bounds__(512) void k_scan(
    const float* __restrict__ xg,   // [B][T][512]
    const float* __restrict__ Wt,   // [128][512]  (= W_hh^T)
    const float* __restrict__ h0, const float* __restrict__ c0,
    const float* __restrict__ g_ih, const float* __restrict__ b_ih,
    const float* __restrict__ g_hh, const float* __restrict__ b_hh,
    const float* __restrict__ g_c,  const float* __restrict__ b_c,
    float* __restrict__ hs)         // [B][T][128]
{
  const int b = blockIdx.x;
  const int g = threadIdx.x;            // 0..511: gate-row index
  const int lane = g & 63, wave = g >> 6;

  __shared__ float h_s[128];
  __shared__ float gates_s[512];
  __shared__ float red[8][4];
  __shared__ float red2[2][2];

  // W_hh row g resident in registers (coalesced load from transposed copy)
  float w[128];
  #pragma unroll
  for (int k = 0; k < 128; ++k) w[k] = Wt[k * 512 + g];

  const float gihv = g_ih[g], bihv = b_ih[g];
  const float ghhv = g_hh[g], bhhv = b_hh[g];
  float gcv = 0.f, bcv = 0.f, cval = 0.f;
  if (g < 128) {
    gcv = g_c[g]; bcv = b_c[g];
    cval = c0[b * 128 + g];
    h_s[g] = h0[b * 128 + g];
  }
  __syncthreads();

  const float* xgb = xg + (size_t)b * 256 * 512;
  float* hsb = hs + (size_t)b * 256 * 128;
  const float inv512 = 1.0f / 512.0f, inv128 = 1.0f / 128.0f;

  for (int t = 0; t < 256; ++t) {
    float xv = xgb[t * 512 + g];
    float acc = 0.f;
    #pragma unroll
    for (int k = 0; k < 128; ++k) acc += w[k] * h_s[k];

    // joint block reduction for both LNs: sums of xv, xv^2, acc, acc^2
    float s0 = xv, s1 = xv * xv, s2 = acc, s3 = acc * acc;
    #pragma unroll
    for (int off = 32; off; off >>= 1) {
      s0 += __shfl_xor(s0, off);
      s1 += __shfl_xor(s1, off);
      s2 += __shfl_xor(s2, off);
      s3 += __shfl_xor(s3, off);
    }
    if (lane == 0) { red[wave][0] = s0; red[wave][1] = s1; red[wave][2] = s2; red[wave][3] = s3; }
    __syncthreads();                                    // barrier 1
    float t0 = 0, t1 = 0, t2 = 0, t3 = 0;
    #pragma unroll
    for (int i2 = 0; i2 < 8; ++i2) { t0 += red[i2][0]; t1 += red[i2][1]; t2 += red[i2][2]; t3 += red[i2][3]; }
    float mx = t0 * inv512, vx = t1 * inv512 - mx * mx;
    float mh = t2 * inv512, vh = t3 * inv512 - mh * mh;
    float lnx = (xv - mx) * rsqrtf(vx + 1e-5f) * gihv + bihv;
    float lnh = (acc - mh) * rsqrtf(vh + 1e-5f) * ghhv + bhhv;
    gates_s[g] = lnx + lnh;
    __syncthreads();                                    // barrier 2

    float cn = 0.f, ov = 0.f;
    if (g < 128) {
      float iv = gates_s[g], fv = gates_s[128 + g], gv = gates_s[256 + g];
      ov = gates_s[384 + g];
      cn = sigm(fv) * cval + sigm(iv) * tanhf(gv);
      cval = cn;
    }
    // LN over c (128 values live in waves 0-1)
    float u0 = cn, u1 = cn * cn;
    #pragma unroll
    for (int off = 32; off; off >>= 1) { u0 += __shfl_xor(u0, off); u1 += __shfl_xor(u1, off); }
    if (g < 128 && lane == 0) { red2[wave][0] = u0; red2[wave][1] = u1; }
    __syncthreads();                                    // barrier 3
    if (g < 128) {
      float sm = red2[0][0] + red2[1][0], sq = red2[0][1] + red2[1][1];
      float mc = sm * inv128, vc = sq * inv128 - mc * mc;
      float lnc = (cn - mc) * rsqrtf(vc + 1e-5f) * gcv + bcv;
      float hn = sigm(ov) * tanhf(lnc);
      h_s[g] = hn;
      hsb[t * 128 + g] = hn;
    }
    __syncthreads();                                    // barrier 4
  }
}

// ---------- k-split reduce + bias + sigmoid ----------
__global__ void k_reduce(const float* __restrict__ part, const float* __restrict__ b_out,
                         float* __restrict__ out) {
  int i = blockIdx.x * 256 + threadIdx.x;   // 0..32767 = b*256+o
  float s = b_out[i & 255];
  #pragma unroll
  for (int z = 0; z < 32; ++z) s += part[(size_t)z * 32768 + i];
  out[i] = sigm(s);
}

extern "C" void kernel_launch(void* const* d_in, const int* in_sizes, int n_in,
                              void* d_out, int out_size, void* d_ws, size_t ws_size,
                              hipStream_t stream) {
  const int*   idx   = (const int*)  d_in[0];
  const float* h0    = (const float*)d_in[1];
  const float* c0    = (const float*)d_in[2];
  const float* table = (const float*)d_in[3];
  const float* W_ih  = (const float*)d_in[4];
  const float* W_hh  = (const float*)d_in[5];
  const float* g_ih  = (const float*)d_in[6];
  const float* b_ih  = (const float*)d_in[7];
  const float* g_hh  = (const float*)d_in[8];
  const float* b_hh  = (const float*)d_in[9];
  const float* g_c   = (const float*)d_in[10];
  const float* b_c   = (const float*)d_in[11];
  const float* W_out = (const float*)d_in[12];
  const float* b_out = (const float*)d_in[13];

  float* out  = (float*)d_out;             // 32768
  float* emb  = out + 32768;               // 4194304 (output #2)
  float* ws   = (float*)d_ws;
  float* xg   = ws;                        // 16777216 floats
  float* hsb  = ws + 16777216;             // 4194304
  float* wt   = ws + 20971520;             // 65536
  float* part = ws + 21037056;             // 1048576

  k_embed<<<4096, 256, 0, stream>>>(idx, (const float4*)table, (float4*)emb);
  k_transpose<<<256, 256, 0, stream>>>(W_hh, wt);
  // x_gates[32768,512] = emb[32768,128] @ W_ih[512,128]^T
  k_gemm_tn<<<dim3(512, 8, 1), 256, 0, stream>>>(emb, W_ih, xg, 128, 2, 512, 0);
  k_scan<<<128, 512, 0, stream>>>(xg, wt, h0, c0, g_ih, b_ih, g_hh, b_hh, g_c, b_c, hsb);
  // partials[32][128,256] = hs[128,32768] @ W_out[256,32768]^T  (k-split 32)
  k_gemm_tn<<<dim3(2, 4, 32), 256, 0, stream>>>(hsb, W_out, part, 32768, 16, 256, 32768);
  k_reduce<<<128, 256, 0, stream>>>(part, b_out, out);
}

// Round 2
// 611.893 us; speedup vs baseline: 1.1422x; 1.1422x over previous
//
#include <hip/hip_runtime.h>
#include <cstddef>

// Shapes: B=128, T=256, H=128, 4H=512, D=2E=128, GENOME=1e6, OUT*T=256, K_out=32768
// d_out: out[128][256] (32768 f32) then emb[128][256][128] (4194304 f32)
// ws (floats): xg @0 (16777216) | hs @16777216 (4194304) | WhhT @20971520 (65536)
//              | partials @21037056 (1048576; xm/xr alias its head during scan)

__device__ __forceinline__ float frcp(float x) { return __builtin_amdgcn_rcpf(x); }
__device__ __forceinline__ float sigm(float x) { return frcp(1.0f + __expf(-x)); }
__device__ __forceinline__ float ftanh(float x) {
  float e = __expf(2.0f * x);
  return (e - 1.0f) * frcp(e + 1.0f);
}

// ---------- embedding gather ----------
__global__ void k_embed(const int* __restrict__ idx, const float4* __restrict__ table4,
                        float4* __restrict__ emb4) {
  int i = blockIdx.x * blockDim.x + threadIdx.x;   // B*T*2*16 = 1,048,576
  int p = i >> 4, j = i & 15;
  int id = idx[p];
  emb4[(size_t)p * 16 + j] = table4[(size_t)id * 16 + j];
}

// ---------- W_hh (512x128) -> WhhT (128x512) ----------
__global__ void k_transpose(const float* __restrict__ W, float* __restrict__ Wt) {
  int i = blockIdx.x * 256 + threadIdx.x;          // 65536
  int g = i >> 7, k = i & 127;
  Wt[k * 512 + g] = W[i];
}

// ---------- generic C[M,N] = A[M,K] @ B[N,K]^T, 64x64 tile ----------
__global__ __launch_bounds__(256) void k_gemm_tn(
    const float* __restrict__ A, const float* __restrict__ Bm, float* __restrict__ C,
    int K, int kchunks, int N, size_t partstride)
{
  __shared__ float As[64][65];
  __shared__ float Bs[64][68];
  const int tid = threadIdx.x;
  const int tx = tid & 15, ty = tid >> 4;
  const int m0 = blockIdx.x * 64, n0 = blockIdx.y * 64;
  float acc[4][4] = {};
  size_t kbase = (size_t)blockIdx.z * kchunks * 64;
  for (int kc = 0; kc < kchunks; ++kc) {
    size_t k0 = kbase + (size_t)kc * 64;
    #pragma unroll
    for (int it = 0; it < 4; ++it) {
      int fi = it * 256 + tid;
      int row = fi >> 4, col4 = fi & 15;
      float4 va = *(const float4*)(A + (size_t)(m0 + row) * K + k0 + col4 * 4);
      As[row][col4*4+0] = va.x; As[row][col4*4+1] = va.y;
      As[row][col4*4+2] = va.z; As[row][col4*4+3] = va.w;
      float4 vb = *(const float4*)(Bm + (size_t)(n0 + row) * K + k0 + col4 * 4);
      Bs[col4*4+0][row] = vb.x; Bs[col4*4+1][row] = vb.y;
      Bs[col4*4+2][row] = vb.z; Bs[col4*4+3][row] = vb.w;
    }
    __syncthreads();
    #pragma unroll 8
    for (int k = 0; k < 64; ++k) {
      float a0 = As[ty*4+0][k], a1 = As[ty*4+1][k], a2 = As[ty*4+2][k], a3 = As[ty*4+3][k];
      float b0 = Bs[k][tx*4+0], b1 = Bs[k][tx*4+1], b2 = Bs[k][tx*4+2], b3 = Bs[k][tx*4+3];
      acc[0][0] += a0*b0; acc[0][1] += a0*b1; acc[0][2] += a0*b2; acc[0][3] += a0*b3;
      acc[1][0] += a1*b0; acc[1][1] += a1*b1; acc[1][2] += a1*b2; acc[1][3] += a1*b3;
      acc[2][0] += a2*b0; acc[2][1] += a2*b1; acc[2][2] += a2*b2; acc[2][3] += a2*b3;
      acc[3][0] += a3*b0; acc[3][1] += a3*b1; acc[3][2] += a3*b2; acc[3][3] += a3*b3;
    }
    __syncthreads();
  }
  float* Cp = C + (size_t)blockIdx.z * partstride;
  #pragma unroll
  for (int i = 0; i < 4; ++i) {
    float4 v = make_float4(acc[i][0], acc[i][1], acc[i][2], acc[i][3]);
    *(float4*)(Cp + (size_t)(m0 + ty*4 + i) * N + n0 + tx*4) = v;
  }
}

// ---------- per-row LN stats of xg: mean & rsqrt(var+eps), one wave per row ----------
__global__ __launch_bounds__(256) void k_xstats(const float4* __restrict__ xg4,
                                                float* __restrict__ xm, float* __restrict__ xr) {
  int row = blockIdx.x * 4 + (threadIdx.x >> 6);   // 32768 rows
  int lane = threadIdx.x & 63;
  const float4* r = xg4 + (size_t)row * 128;
  float4 a = r[lane], b = r[lane + 64];
  float s = a.x + a.y + a.z + a.w + b.x + b.y + b.z + b.w;
  float q = a.x*a.x + a.y*a.y + a.z*a.z + a.w*a.w + b.x*b.x + b.y*b.y + b.z*b.z + b.w*b.w;
  #pragma unroll
  for (int off = 32; off; off >>= 1) { s += __shfl_xor(s, off); q += __shfl_xor(q, off); }
  if (lane == 0) {
    float m = s * (1.0f / 512.0f);
    xm[row] = m;
    xr[row] = rsqrtf(q * (1.0f / 512.0f) - m * m + 1e-5f);
  }
}

// ---------- persistent LSTM scan: one block per batch row, 512 threads, 1 barrier/step ----------
__global__ __launch_bounds__(512, 2) void k_scan(
    const float* __restrict__ xg,   // [B][T][512]
    const float* __restrict__ Wt,   // [128][512]  (= W_hh^T)
    const float* __restrict__ xm, const float* __restrict__ xr,   // [B*T]
    const float* __restrict__ h0, const float* __restrict__ c0,
    const float* __restrict__ g_ih, const float* __restrict__ b_ih,
    const float* __restrict__ g_hh, const float* __restrict__ b_hh,
    const float* __restrict__ g_c,  const float* __restrict__ b_c,
    float* __restrict__ hs)         // [B][T][128]
{
  const int b = blockIdx.x;
  const int g = threadIdx.x;            // 0..511: gate-row index
  const int lane = g & 63, wave = g >> 6;

  __shared__ float xv_s[2][512];
  __shared__ float acc_s[2][512];
  __shared__ float2 red_s[2][8];
  __shared__ float4 h4_s[8][32];        // per-wave private h copy (128 floats each)

  // --- W_hh row g resident in VGPRs (coalesced from transposed copy), pinned ---
  float4 w4[32];
  #pragma unroll
  for (int k = 0; k < 32; ++k) {
    w4[k].x = Wt[(4*k+0) * 512 + g];
    w4[k].y = Wt[(4*k+1) * 512 + g];
    w4[k].z = Wt[(4*k+2) * 512 + g];
    w4[k].w = Wt[(4*k+3) * 512 + g];
  }
  #pragma unroll
  for (int k = 0; k < 32; ++k)
    asm volatile("" : "+v"(w4[k].x), "+v"(w4[k].y), "+v"(w4[k].z), "+v"(w4[k].w));

  // per-lane gate params at positions j*64+lane (j: 0..7 -> i,i,f,f,g,g,o,o halves)
  float gih[8], bih[8], ghh[8], bhh[8];
  #pragma unroll
  for (int j = 0; j < 8; ++j) {
    gih[j] = g_ih[j*64 + lane]; bih[j] = b_ih[j*64 + lane];
    ghh[j] = g_hh[j*64 + lane]; bhh[j] = b_hh[j*64 + lane];
  }
  float gc0 = g_c[lane], bc0 = b_c[lane], gc1 = g_c[64 + lane], bc1 = b_c[64 + lane];
  float cv0 = c0[b*128 + lane], cv1 = c0[b*128 + 64 + lane];

  float* hown = (float*)&h4_s[wave][0];
  hown[lane]      = h0[b*128 + lane];
  hown[64 + lane] = h0[b*128 + 64 + lane];

  const float* xgb = xg + (size_t)b * 256 * 512;
  const float* xmb = xm + b * 256;
  const float* xrb = xr + b * 256;
  float* hsb = hs + (size_t)b * 256 * 128;

  for (int t = 0; t < 256; ++t) {
    const int buf = t & 1;
    float xv = xgb[t*512 + g];
    xv_s[buf][g] = xv;
    float mx = xmb[t], rx = xrb[t];     // wave-uniform scalar loads

    // matvec: acc_g = W_hh[g,:] . h  (h broadcast from this wave's own LDS copy)
    float a0 = 0.f, a1 = 0.f, a2 = 0.f, a3 = 0.f;
    #pragma unroll
    for (int k = 0; k < 32; ++k) {
      float4 h4 = h4_s[wave][k];
      a0 += w4[k].x * h4.x; a1 += w4[k].y * h4.y;
      a2 += w4[k].z * h4.z; a3 += w4[k].w * h4.w;
    }
    float acc = (a0 + a1) + (a2 + a3);
    acc_s[buf][g] = acc;

    float s = acc, q = acc * acc;
    #pragma unroll
    for (int off = 32; off; off >>= 1) { s += __shfl_xor(s, off); q += __shfl_xor(q, off); }
    if (lane == 0) red_s[buf][wave] = make_float2(s, q);

    __syncthreads();                    // the ONE barrier per step

    float rsx = 0.f, rsq = 0.f;
    #pragma unroll
    for (int i = 0; i < 8; ++i) { float2 v = red_s[buf][i]; rsx += v.x; rsq += v.y; }
    float mh = rsx * (1.0f/512.0f), vh = rsq * (1.0f/512.0f) - mh * mh;
    float rh = rsqrtf(vh + 1e-5f);

    // c/h path: every wave redundantly computes the full 128-vector
    float gv[8];
    #pragma unroll
    for (int j = 0; j < 8; ++j) {
      int p = j*64 + lane;
      float lx = (xv_s[buf][p]  - mx) * rx * gih[j] + bih[j];
      float lh = (acc_s[buf][p] - mh) * rh * ghh[j] + bhh[j];
      gv[j] = lx + lh;
    }
    // idx lane: i=gv[0], f=gv[2], g=gv[4], o=gv[6]; idx 64+lane: gv[1],gv[3],gv[5],gv[7]
    float cn0 = sigm(gv[2]) * cv0 + sigm(gv[0]) * ftanh(gv[4]);
    float cn1 = sigm(gv[3]) * cv1 + sigm(gv[1]) * ftanh(gv[5]);
    cv0 = cn0; cv1 = cn1;

    float cs = cn0 + cn1, cq = cn0*cn0 + cn1*cn1;
    #pragma unroll
    for (int off = 32; off; off >>= 1) { cs += __shfl_xor(cs, off); cq += __shfl_xor(cq, off); }
    float mc = cs * (1.0f/128.0f), vc = cq * (1.0f/128.0f) - mc * mc;
    float rc = rsqrtf(vc + 1e-5f);

    float hn0 = sigm(gv[6]) * ftanh((cn0 - mc) * rc * gc0 + bc0);
    float hn1 = sigm(gv[7]) * ftanh((cn1 - mc) * rc * gc1 + bc1);
    hown[lane]      = hn0;
    hown[64 + lane] = hn1;
    if (wave == 0) { hsb[t*128 + lane] = hn0; hsb[t*128 + 64 + lane] = hn1; }
  }
}

// ---------- k-split reduce + bias + sigmoid ----------
__global__ void k_reduce(const float* __restrict__ part, const float* __restrict__ b_out,
                         float* __restrict__ out) {
  int i = blockIdx.x * 256 + threadIdx.x;   // 0..32767 = b*256+o
  float s = b_out[i & 255];
  #pragma unroll
  for (int z = 0; z < 32; ++z) s += part[(size_t)z * 32768 + i];
  out[i] = sigm(s);
}

extern "C" void kernel_launch(void* const* d_in, const int* in_sizes, int n_in,
                              void* d_out, int out_size, void* d_ws, size_t ws_size,
                              hipStream_t stream) {
  const int*   idx   = (const int*)  d_in[0];
  const float* h0    = (const float*)d_in[1];
  const float* c0    = (const float*)d_in[2];
  const float* table = (const float*)d_in[3];
  const float* W_ih  = (const float*)d_in[4];
  const float* W_hh  = (const float*)d_in[5];
  const float* g_ih  = (const float*)d_in[6];
  const float* b_ih  = (const float*)d_in[7];
  const float* g_hh  = (const float*)d_in[8];
  const float* b_hh  = (const float*)d_in[9];
  const float* g_c   = (const float*)d_in[10];
  const float* b_c   = (const float*)d_in[11];
  const float* W_out = (const float*)d_in[12];
  const float* b_out = (const float*)d_in[13];

  float* out  = (float*)d_out;             // 32768
  float* emb  = out + 32768;               // 4194304 (output #2)
  float* ws   = (float*)d_ws;
  float* xg   = ws;                        // 16777216 floats
  float* hsb  = ws + 16777216;             // 4194304
  float* wt   = ws + 20971520;             // 65536
  float* part = ws + 21037056;             // 1048576
  float* xmv  = part;                      // 32768 (aliases part; dead before part written)
  float* xrv  = part + 32768;              // 32768

  k_embed<<<4096, 256, 0, stream>>>(idx, (const float4*)table, (float4*)emb);
  k_transpose<<<256, 256, 0, stream>>>(W_hh, wt);
  // x_gates[32768,512] = emb[32768,128] @ W_ih[512,128]^T
  k_gemm_tn<<<dim3(512, 8, 1), 256, 0, stream>>>(emb, W_ih, xg, 128, 2, 512, 0);
  k_xstats<<<8192, 256, 0, stream>>>((const float4*)xg, xmv, xrv);
  k_scan<<<128, 512, 0, stream>>>(xg, wt, xmv, xrv, h0, c0, g_ih, b_ih, g_hh, b_hh, g_c, b_c, hsb);
  // partials[32][128,256] = hs[128,32768] @ W_out[256,32768]^T  (k-split 32)
  k_gemm_tn<<<dim3(2, 4, 32), 256, 0, stream>>>(hsb, W_out, part, 32768, 16, 256, 32768);
  k_reduce<<<128, 256, 0, stream>>>(part, b_out, out);
}